// Round 3
// baseline (603.699 us; speedup 1.0000x reference)
//
#include <hip/hip_runtime.h>

#define Bb 1024
#define Ss 512
#define Ee 128
#define Hh 256
#define Vv 128
#define Cc 18

// Dynamic LDS layout (122880 B total):
#define H1OFF 8192    // h double buffer: [0,8192) and [8192,16384), 16 rows x 512B, XOR-swizzled
#define YOFF  16384   // y bf16 capture: 8192 B (same layout as one h buffer)
#define TOFF  24576   // T bf16: 128 rows x 512 B, XOR-swizzled: byte v*512 + ((j*2)^((v&7)<<4))
#define XOFF  90112   // x transposed [512][16] int = 32768 B; z f32 [16][256] aliases after loop
#define SMEM_BYTES 122880

typedef __attribute__((ext_vector_type(8))) short short8;
typedef __attribute__((ext_vector_type(4))) float f32x4;
typedef __attribute__((ext_vector_type(2))) int int2v;
typedef __attribute__((ext_vector_type(4))) int int4v;

__device__ __forceinline__ unsigned short f2bf(float f) {
  union { float f; unsigned u; } v; v.f = f;
  return (unsigned short)((v.u + 0x7FFFu + ((v.u >> 16) & 1u)) >> 16);
}

__device__ __forceinline__ f32x4 mfma16(short8 a, short8 b, f32x4 c) {
  return __builtin_amdgcn_mfma_f32_16x16x32_bf16(a, b, c, 0, 0, 0);
}

// tanh = 1 - 2/(e^{2x}+1); correct limits at +-inf, no clamp needed.
__device__ __forceinline__ float ftanh(float x) {
  float e2 = __expf(2.0f * x);
  return 1.0f - 2.0f * __builtin_amdgcn_rcpf(e2 + 1.0f);
}

__device__ __forceinline__ unsigned cvtpk(float a, float b) {
  unsigned r;
  asm("v_cvt_pk_bf16_f32 %0, %1, %2" : "=v"(r) : "v"(a), "v"(b));
  return r;  // lo16 = bf16(a), hi16 = bf16(b)
}

// Load a 64-col slice of a [256][256] f32 row-major matrix as bf16 A-fragments.
__device__ __forceinline__ void load_wfrags(const float* __restrict__ W, int j0, int l15, int g,
                                            short8 wfrag[4][8]) {
#pragma unroll
  for (int mt = 0; mt < 4; ++mt) {
    const float* wrow = W + (j0 + mt * 16 + l15) * Hh;
#pragma unroll
    for (int kt = 0; kt < 8; ++kt) {
      const float* wp = wrow + kt * 32 + g * 8;
      f32x4 a = *(const f32x4*)(wp);
      f32x4 b = *(const f32x4*)(wp + 4);
      short8 f;
      f[0] = (short)f2bf(a.x); f[1] = (short)f2bf(a.y);
      f[2] = (short)f2bf(a.z); f[3] = (short)f2bf(a.w);
      f[4] = (short)f2bf(b.x); f[5] = (short)f2bf(b.y);
      f[6] = (short)f2bf(b.z); f[7] = (short)f2bf(b.w);
      wfrag[mt][kt] = f;
    }
  }
}

// ---------------- Kernel 1: T[v][j] = emb[v].W_ih[j] + b_ih[j] + b_hh[j], bf16, pre-swizzled ----------------
__global__ void prep_T2(const float* __restrict__ emb, const float* __restrict__ W_ih,
                        const float* __restrict__ b_ih, const float* __restrict__ b_hh,
                        unsigned short* __restrict__ Tg) {
  __shared__ float elds[Ee];
  const int v = blockIdx.x, j = threadIdx.x;
  if (j < Ee) elds[j] = emb[v * Ee + j];
  __syncthreads();
  float s = b_ih[j] + b_hh[j];
  const float* wr = W_ih + j * Ee;
#pragma unroll 8
  for (int e = 0; e < Ee; e += 4) {
    f32x4 w = *(const f32x4*)(wr + e);
    f32x4 x = *(const f32x4*)(elds + e);
    s += w.x * x.x + w.y * x.y + w.z * x.z + w.w * x.w;
  }
  // swizzle baked in: u16 index j ^ ((v&7)<<3)  (== byte (j*2)^((v&7)<<4))
  Tg[v * Hh + (j ^ ((v & 7) << 3))] = f2bf(s);
}

// ---------------- one RNN step (PAR = parity selects read/write h buffer) ----------------
template <int PAR>
__device__ __forceinline__ void step_phase(char* smem, const short8 (&wf)[4][8],
                                           const int (&roff)[8], const int (&woff)[4],
                                           const int (&cb)[4], const f32x4& Z4,
                                           int t, int mylen, int r, int& xv) {
  char* RB = smem + (PAR ? H1OFF : 0);
  char* WB = smem + (PAR ? 0 : H1OFF);

  // h_t B-fragments (swizzled ds_read_b128)
  short8 hf[8];
#pragma unroll
  for (int kt = 0; kt < 8; ++kt) hf[kt] = *(const short8*)(RB + roff[kt]);

  // T rows for this step's tokens (per-lane row xv), swizzled ds_read_b64
  const int tbase = TOFF + (xv << 9);
  const int tsw   = (xv & 7) << 4;
  int2v tw[4];
#pragma unroll
  for (int mt = 0; mt < 4; ++mt)
    tw[mt] = *(const int2v*)(smem + tbase + (cb[mt] ^ tsw));

  // next token (conflict-free: 16 consecutive dwords, 4-lane broadcast)
  const int tn  = (t + 1 < Ss) ? t + 1 : Ss - 1;
  const int xvn = *(const int*)(smem + XOFF + ((tn * 16 + r) << 2));

  // unpack T bf16 -> f32 (2 ops per pair)
  f32x4 tq[4];
#pragma unroll
  for (int mt = 0; mt < 4; ++mt) {
    tq[mt].x = __int_as_float(tw[mt].x << 16);
    tq[mt].y = __int_as_float(tw[mt].x & 0xffff0000);
    tq[mt].z = __int_as_float(tw[mt].y << 16);
    tq[mt].w = __int_as_float(tw[mt].y & 0xffff0000);
  }

  // 16 independent MFMA chains of depth 2; A-chain seeded with T (no acc init cost)
  f32x4 aA[4], aB[4], aC[4], aD[4];
#pragma unroll
  for (int mt = 0; mt < 4; ++mt) {
    aB[mt] = mfma16(wf[mt][2], hf[2], Z4);
    aC[mt] = mfma16(wf[mt][4], hf[4], Z4);
    aD[mt] = mfma16(wf[mt][6], hf[6], Z4);
    aA[mt] = mfma16(wf[mt][0], hf[0], tq[mt]);
  }
#pragma unroll
  for (int mt = 0; mt < 4; ++mt) {
    aB[mt] = mfma16(wf[mt][3], hf[3], aB[mt]);
    aC[mt] = mfma16(wf[mt][5], hf[5], aC[mt]);
    aD[mt] = mfma16(wf[mt][7], hf[7], aD[mt]);
    aA[mt] = mfma16(wf[mt][1], hf[1], aA[mt]);
  }

  const bool emit = (t == mylen - 1);
#pragma unroll
  for (int mt = 0; mt < 4; ++mt) {
    float s0 = (aA[mt].x + aB[mt].x) + (aC[mt].x + aD[mt].x);
    float s1 = (aA[mt].y + aB[mt].y) + (aC[mt].y + aD[mt].y);
    float s2 = (aA[mt].z + aB[mt].z) + (aC[mt].z + aD[mt].z);
    float s3 = (aA[mt].w + aB[mt].w) + (aC[mt].w + aD[mt].w);
    int2v pk;
    pk.x = (int)cvtpk(ftanh(s0), ftanh(s1));
    pk.y = (int)cvtpk(ftanh(s2), ftanh(s3));
    *(int2v*)(WB + woff[mt]) = pk;
    if (emit) *(int2v*)(smem + YOFF + woff[mt]) = pk;
  }

  xv = xvn;
  // raw barrier: only LDS must drain (no vmem in the loop at all)
  asm volatile("s_waitcnt lgkmcnt(0)" ::: "memory");
  __builtin_amdgcn_sched_barrier(0);
  __builtin_amdgcn_s_barrier();
  __builtin_amdgcn_sched_barrier(0);
}

// ---------------- Kernel 2: recurrence + fused FC head ----------------
__global__ __launch_bounds__(256, 1)
void rnn_fused(const int* __restrict__ x_in, const int* __restrict__ x_len,
               const float* __restrict__ W_hh, const unsigned short* __restrict__ Tg,
               const float* __restrict__ fc1_w, const float* __restrict__ fc1_b,
               const float* __restrict__ fc2_w, const float* __restrict__ fc2_b,
               float* __restrict__ out) {
  extern __shared__ __align__(16) char smem[];

  const int tid  = threadIdx.x;
  const int lane = tid & 63;
  const int wave = tid >> 6;
  const int l15  = lane & 15;
  const int g    = lane >> 4;        // 0..3
  const int j0   = wave * 64;
  const int grow = blockIdx.x * 16;
  const int r    = l15;              // this lane's batch row
  const int swz  = (r & 7) << 4;
  const int rowb = r * 512;

  // W_hh fragments resident in registers (overlaps the LDS staging below)
  short8 wfrag[4][8];
  load_wfrags(W_hh, j0, l15, g, wfrag);

  const int mylen = x_len[grow + r];
  int maxlen = 1;
#pragma unroll
  for (int i = 0; i < 16; ++i) maxlen = max(maxlen, x_len[grow + i]);

  // stage T (64KB linear copy; swizzle pre-baked by prep_T2)
  {
    const int4v* Tsrc = (const int4v*)Tg;
    int4v* Tdst = (int4v*)(smem + TOFF);
    for (int i = tid; i < 4096; i += 256) Tdst[i] = Tsrc[i];
  }
  // stage x transposed: x_tr[t][r]
  {
    int* xtr = (int*)(smem + XOFF);
    for (int i = tid; i < 16 * Ss; i += 256) {
      int rr = i >> 9, tt = i & 511;
      xtr[tt * 16 + rr] = x_in[(grow + rr) * Ss + tt];
    }
  }
  // zero h buffer 0
  {
    int4v* hz = (int4v*)smem;
    const int4v z4 = {0, 0, 0, 0};
    for (int i = tid; i < 512; i += 256) hz[i] = z4;
  }
  __syncthreads();

  // precomputed LDS byte offsets
  int roff[8], woff[4], cb[4];
#pragma unroll
  for (int kt = 0; kt < 8; ++kt) roff[kt] = rowb + ((kt * 64 + g * 16) ^ swz);
#pragma unroll
  for (int mt = 0; mt < 4; ++mt) woff[mt] = rowb + (((j0 + mt * 16 + g * 4) * 2) ^ swz);
#pragma unroll
  for (int mt = 0; mt < 4; ++mt) cb[mt] = (j0 + mt * 16 + g * 4) * 2;

  const f32x4 Z4 = {0.f, 0.f, 0.f, 0.f};
  int xv = *(const int*)(smem + XOFF + (r << 2));  // token 0

  const int mx2 = (maxlen + 1) & ~1;  // even #steps; extra step writes an unread buffer
  for (int t = 0; t < mx2; t += 2) {
    step_phase<0>(smem, wfrag, roff, woff, cb, Z4, t,     mylen, r, xv);
    step_phase<1>(smem, wfrag, roff, woff, cb, Z4, t + 1, mylen, r, xv);
  }

  // ---------------- fused FC head ----------------
  short8 ffrag[4][8];
  load_wfrags(fc1_w, j0, l15, g, ffrag);
  f32x4 fb[4];
#pragma unroll
  for (int mt = 0; mt < 4; ++mt)
    fb[mt] = *(const f32x4*)(fc1_b + j0 + mt * 16 + g * 4);

  short8 yf[8];
#pragma unroll
  for (int kt = 0; kt < 8; ++kt) yf[kt] = *(const short8*)(smem + YOFF + roff[kt]);

  f32x4 acc[4], acc2[4];
#pragma unroll
  for (int mt = 0; mt < 4; ++mt) { acc[mt] = fb[mt]; acc2[mt] = Z4; }
#pragma unroll
  for (int kt = 0; kt < 4; ++kt)
#pragma unroll
    for (int mt = 0; mt < 4; ++mt)
      acc[mt] = mfma16(ffrag[mt][kt], yf[kt], acc[mt]);
#pragma unroll
  for (int kt = 4; kt < 8; ++kt)
#pragma unroll
    for (int mt = 0; mt < 4; ++mt)
      acc2[mt] = mfma16(ffrag[mt][kt], yf[kt], acc2[mt]);

  float* z_ld = (float*)(smem + XOFF);  // alias x_tr (all x reads done)
#pragma unroll
  for (int mt = 0; mt < 4; ++mt) {
    f32x4 z;
    z.x = fmaxf(acc[mt].x + acc2[mt].x, 0.f);
    z.y = fmaxf(acc[mt].y + acc2[mt].y, 0.f);
    z.z = fmaxf(acc[mt].z + acc2[mt].z, 0.f);
    z.w = fmaxf(acc[mt].w + acc2[mt].w, 0.f);
    *(f32x4*)(z_ld + r * 256 + j0 + mt * 16 + g * 4) = z;
  }
  __syncthreads();

  // fc2: 16 rows x 18 classes
  for (int idx = tid; idx < 16 * Cc; idx += 256) {
    const int rr = idx / Cc, c = idx % Cc;
    float s = fc2_b[c];
    const float* wr2 = fc2_w + c * Hh;
    const float* zr  = z_ld + rr * 256;
#pragma unroll 4
    for (int k = 0; k < Hh; k += 4) {
      f32x4 w = *(const f32x4*)(wr2 + k);
      f32x4 z = *(const f32x4*)(zr + k);
      s += w.x * z.x + w.y * z.y + w.z * z.z + w.w * z.w;
    }
    out[(grow + rr) * Cc + c] = s;
  }
}

extern "C" void kernel_launch(void* const* d_in, const int* in_sizes, int n_in,
                              void* d_out, int out_size, void* d_ws, size_t ws_size,
                              hipStream_t stream) {
  const int*   x_in  = (const int*)d_in[0];
  const int*   x_len = (const int*)d_in[1];
  const float* emb   = (const float*)d_in[2];
  const float* W_ih  = (const float*)d_in[3];
  const float* W_hh  = (const float*)d_in[4];
  const float* b_ih  = (const float*)d_in[5];
  const float* b_hh  = (const float*)d_in[6];
  const float* fc1_w = (const float*)d_in[7];
  const float* fc1_b = (const float*)d_in[8];
  const float* fc2_w = (const float*)d_in[9];
  const float* fc2_b = (const float*)d_in[10];
  float* out = (float*)d_out;

  unsigned short* Tg = (unsigned short*)d_ws;  // 128*256 bf16 = 64 KB

  hipFuncSetAttribute((const void*)rnn_fused,
                      hipFuncAttributeMaxDynamicSharedMemorySize, SMEM_BYTES);

  prep_T2<<<Vv, Hh, 0, stream>>>(emb, W_ih, b_ih, b_hh, Tg);
  rnn_fused<<<Bb / 16, 256, SMEM_BYTES, stream>>>(x_in, x_len, W_hh, Tg,
                                                  fc1_w, fc1_b, fc2_w, fc2_b, out);
}

// Round 5
// 498.249 us; speedup vs baseline: 1.2116x; 1.2116x over previous
//
#include <hip/hip_runtime.h>

#define Bb 1024
#define Ss 512
#define Ee 128
#define Hh 256
#define Vv 128
#define Cc 18

// Static LDS map (40960 B):
#define H1OFF 8192    // h double buffer: [0,8192) + [8192,16384), 16 rows x 512B, XOR-swizzled
#define YOFF  16384   // y bf16 capture: 8192 B (same layout/swizzle as one h buffer)
#define ZOFF  24576   // z f32 [16][256] for the FC head

typedef __attribute__((ext_vector_type(8))) short short8;
typedef __attribute__((ext_vector_type(4))) float f32x4;
typedef __attribute__((ext_vector_type(2))) int int2v;

__device__ __forceinline__ unsigned short f2bf(float f) {
  union { float f; unsigned u; } v; v.f = f;
  return (unsigned short)((v.u + 0x7FFFu + ((v.u >> 16) & 1u)) >> 16);
}

__device__ __forceinline__ f32x4 mfma16(short8 a, short8 b, f32x4 c) {
  return __builtin_amdgcn_mfma_f32_16x16x32_bf16(a, b, c, 0, 0, 0);
}

// tanh = 1 - 2/(e^{2x}+1); correct limits at +-inf, no clamp needed.
__device__ __forceinline__ float ftanh(float x) {
  float e2 = __expf(2.0f * x);
  return 1.0f - 2.0f * __builtin_amdgcn_rcpf(e2 + 1.0f);
}

__device__ __forceinline__ unsigned cvtpk(float a, float b) {
  unsigned r;
  asm("v_cvt_pk_bf16_f32 %0, %1, %2" : "=v"(r) : "v"(a), "v"(b));
  return r;  // lo16 = bf16(a), hi16 = bf16(b)
}

// Load a 64-col slice of a [256][256] f32 row-major matrix as bf16 A-fragments.
__device__ __forceinline__ void load_wfrags(const float* __restrict__ W, int j0, int l15, int g,
                                            short8 wfrag[4][8]) {
#pragma unroll
  for (int mt = 0; mt < 4; ++mt) {
    const float* wrow = W + (j0 + mt * 16 + l15) * Hh;
#pragma unroll
    for (int kt = 0; kt < 8; ++kt) {
      const float* wp = wrow + kt * 32 + g * 8;
      f32x4 a = *(const f32x4*)(wp);
      f32x4 b = *(const f32x4*)(wp + 4);
      short8 f;
      f[0] = (short)f2bf(a.x); f[1] = (short)f2bf(a.y);
      f[2] = (short)f2bf(a.z); f[3] = (short)f2bf(a.w);
      f[4] = (short)f2bf(b.x); f[5] = (short)f2bf(b.y);
      f[6] = (short)f2bf(b.z); f[7] = (short)f2bf(b.w);
      wfrag[mt][kt] = f;
    }
  }
}

// ---------------- Kernel 1: T[v][j] = emb[v].W_ih[j] + b_ih[j] + b_hh[j] (f32) ----------------
__global__ void prep_T(const float* __restrict__ emb, const float* __restrict__ W_ih,
                       const float* __restrict__ b_ih, const float* __restrict__ b_hh,
                       float* __restrict__ T) {
  __shared__ float elds[Ee];
  const int v = blockIdx.x, j = threadIdx.x;
  if (j < Ee) elds[j] = emb[v * Ee + j];
  __syncthreads();
  float s = b_ih[j] + b_hh[j];
  const float* wr = W_ih + j * Ee;
#pragma unroll 8
  for (int e = 0; e < Ee; e += 4) {
    f32x4 w = *(const f32x4*)(wr + e);
    f32x4 x = *(const f32x4*)(elds + e);
    s += w.x * x.x + w.y * x.y + w.z * x.z + w.w * x.w;
  }
  T[v * Hh + j] = s;
}

// ---------------- one RNN step ----------------
// Pipeline invariants (verified by induction):
//   tcur    = T rows for token x[t]        (consumed this step)
//   xv_use  = x[t+1]                       (drives this step's T prefetch)
//   xv_inf  = x[t+2]                       (token load already resident/in flight)
//   => the token load issued THIS step must be x[t+3].
template <int PAR>
__device__ __forceinline__ void step_phase(char* smem, const short8 (&wf)[4][8],
                                           const int (&roff)[8], const int (&woff)[4],
                                           const float* __restrict__ T,
                                           const int* __restrict__ xrow,
                                           int t, int mylen, int j0, int g,
                                           f32x4 (&tcur)[4], int& xv_use, int& xv_inf) {
  char* RB = smem + (PAR ? H1OFF : 0);
  char* WB = smem + (PAR ? 0 : H1OFF);

  // (1) issue NEXT step's T gather (f32, register destination) + token for t+3.
  //     These complete under this step's MFMA+tanh; no LDS traffic, no drain at barrier.
  const float* tp = T + xv_use * Hh + j0 + g * 4;
  f32x4 tn0 = *(const f32x4*)(tp);
  f32x4 tn1 = *(const f32x4*)(tp + 16);
  f32x4 tn2 = *(const f32x4*)(tp + 32);
  f32x4 tn3 = *(const f32x4*)(tp + 48);
  const int xv_new = xrow[min(t + 3, Ss - 1)];   // FIX: was t+2 (one pipeline stage short)

  // (2) h-reads pipelined 2-ahead into the MFMA stream (fine-grained lgkmcnt)
  short8 hf[8];
  hf[0] = *(const short8*)(RB + roff[0]);
  hf[1] = *(const short8*)(RB + roff[1]);

  f32x4 aA[4], aB[4];
  const f32x4 Z4 = {0.f, 0.f, 0.f, 0.f};
#pragma unroll
  for (int mt = 0; mt < 4; ++mt) { aA[mt] = tcur[mt]; aB[mt] = Z4; }

#pragma unroll
  for (int kt = 0; kt < 8; ++kt) {
    if (kt < 6) hf[kt + 2] = *(const short8*)(RB + roff[kt + 2]);
    if ((kt & 1) == 0) {
#pragma unroll
      for (int mt = 0; mt < 4; ++mt) aA[mt] = mfma16(wf[mt][kt], hf[kt], aA[mt]);
    } else {
#pragma unroll
      for (int mt = 0; mt < 4; ++mt) aB[mt] = mfma16(wf[mt][kt], hf[kt], aB[mt]);
    }
  }

  // (3) per-mt epilogue: combine, tanh, pack, write (writes retire progressively)
  const bool emit = (t == mylen - 1);
#pragma unroll
  for (int mt = 0; mt < 4; ++mt) {
    float s0 = aA[mt].x + aB[mt].x;
    float s1 = aA[mt].y + aB[mt].y;
    float s2 = aA[mt].z + aB[mt].z;
    float s3 = aA[mt].w + aB[mt].w;
    int2v pk;
    pk.x = (int)cvtpk(ftanh(s0), ftanh(s1));
    pk.y = (int)cvtpk(ftanh(s2), ftanh(s3));
    *(int2v*)(WB + woff[mt]) = pk;
    if (emit) *(int2v*)(smem + YOFF + woff[mt]) = pk;
  }

  // rotate the prefetch pipeline (vmcnt waits land here, ~a full step after issue)
  tcur[0] = tn0; tcur[1] = tn1; tcur[2] = tn2; tcur[3] = tn3;
  xv_use = xv_inf;
  xv_inf = xv_new;

  // (4) raw barrier: only the ds_writes must drain
  asm volatile("s_waitcnt lgkmcnt(0)" ::: "memory");
  __builtin_amdgcn_sched_barrier(0);
  __builtin_amdgcn_s_barrier();
  __builtin_amdgcn_sched_barrier(0);
}

// ---------------- Kernel 2: recurrence + fused FC head ----------------
__global__ __launch_bounds__(256, 1)
void rnn_fused(const int* __restrict__ x_in, const int* __restrict__ x_len,
               const float* __restrict__ W_hh, const float* __restrict__ T,
               const float* __restrict__ fc1_w, const float* __restrict__ fc1_b,
               const float* __restrict__ fc2_w, const float* __restrict__ fc2_b,
               float* __restrict__ out) {
  __shared__ __align__(16) char smem[40960];

  const int tid  = threadIdx.x;
  const int lane = tid & 63;
  const int wave = tid >> 6;
  const int l15  = lane & 15;
  const int g    = lane >> 4;        // 0..3
  const int j0   = wave * 64;
  const int grow = blockIdx.x * 16;
  const int r    = l15;              // this lane's batch row
  const int swz  = (r & 7) << 4;
  const int rowb = r * 512;

  // W_hh fragments resident in registers
  short8 wfrag[4][8];
  load_wfrags(W_hh, j0, l15, g, wfrag);

  const int mylen = x_len[grow + r];
  int maxlen = 1;
#pragma unroll
  for (int i = 0; i < 16; ++i) maxlen = max(maxlen, x_len[grow + i]);

  // zero h buffer 0
  {
    int2v* hz = (int2v*)smem;
    const int2v z2 = {0, 0};
    for (int i = tid; i < 1024; i += 256) hz[i] = z2;
  }

  // precomputed LDS byte offsets
  int roff[8], woff[4];
#pragma unroll
  for (int kt = 0; kt < 8; ++kt) roff[kt] = rowb + ((kt * 64 + g * 16) ^ swz);
#pragma unroll
  for (int mt = 0; mt < 4; ++mt) woff[mt] = rowb + (((j0 + mt * 16 + g * 4) * 2) ^ swz);

  // token + T register pipeline prologue
  const int* xrow = x_in + (grow + r) * Ss;
  f32x4 tcur[4];
  {
    const int xv0 = xrow[0];
    const float* tp = T + xv0 * Hh + j0 + g * 4;
    tcur[0] = *(const f32x4*)(tp);
    tcur[1] = *(const f32x4*)(tp + 16);
    tcur[2] = *(const f32x4*)(tp + 32);
    tcur[3] = *(const f32x4*)(tp + 48);
  }
  int xv_use = xrow[min(1, Ss - 1)];   // x[1]
  int xv_inf = xrow[min(2, Ss - 1)];   // x[2]

  __syncthreads();

  const int mx2 = (maxlen + 1) & ~1;  // even #steps; extra step writes an unread buffer
  for (int t = 0; t < mx2; t += 2) {
    step_phase<0>(smem, wfrag, roff, woff, T, xrow, t,     mylen, j0, g, tcur, xv_use, xv_inf);
    step_phase<1>(smem, wfrag, roff, woff, T, xrow, t + 1, mylen, j0, g, tcur, xv_use, xv_inf);
  }

  // ---------------- fused FC head ----------------
  short8 ffrag[4][8];
  load_wfrags(fc1_w, j0, l15, g, ffrag);
  f32x4 fb[4];
#pragma unroll
  for (int mt = 0; mt < 4; ++mt)
    fb[mt] = *(const f32x4*)(fc1_b + j0 + mt * 16 + g * 4);

  short8 yf[8];
#pragma unroll
  for (int kt = 0; kt < 8; ++kt) yf[kt] = *(const short8*)(smem + YOFF + roff[kt]);

  const f32x4 Z4 = {0.f, 0.f, 0.f, 0.f};
  f32x4 acc[4], acc2[4];
#pragma unroll
  for (int mt = 0; mt < 4; ++mt) { acc[mt] = fb[mt]; acc2[mt] = Z4; }
#pragma unroll
  for (int kt = 0; kt < 4; ++kt)
#pragma unroll
    for (int mt = 0; mt < 4; ++mt)
      acc[mt] = mfma16(ffrag[mt][kt], yf[kt], acc[mt]);
#pragma unroll
  for (int kt = 4; kt < 8; ++kt)
#pragma unroll
    for (int mt = 0; mt < 4; ++mt)
      acc2[mt] = mfma16(ffrag[mt][kt], yf[kt], acc2[mt]);

  float* z_ld = (float*)(smem + ZOFF);
#pragma unroll
  for (int mt = 0; mt < 4; ++mt) {
    f32x4 z;
    z.x = fmaxf(acc[mt].x + acc2[mt].x, 0.f);
    z.y = fmaxf(acc[mt].y + acc2[mt].y, 0.f);
    z.z = fmaxf(acc[mt].z + acc2[mt].z, 0.f);
    z.w = fmaxf(acc[mt].w + acc2[mt].w, 0.f);
    *(f32x4*)(z_ld + r * 256 + j0 + mt * 16 + g * 4) = z;
  }
  __syncthreads();

  // fc2: 16 rows x 18 classes
  for (int idx = tid; idx < 16 * Cc; idx += 256) {
    const int rr = idx / Cc, c = idx % Cc;
    float s = fc2_b[c];
    const float* wr2 = fc2_w + c * Hh;
    const float* zr  = z_ld + rr * 256;
#pragma unroll 4
    for (int k = 0; k < Hh; k += 4) {
      f32x4 w = *(const f32x4*)(wr2 + k);
      f32x4 z = *(const f32x4*)(zr + k);
      s += w.x * z.x + w.y * z.y + w.z * z.z + w.w * z.w;
    }
    out[(grow + rr) * Cc + c] = s;
  }
}

extern "C" void kernel_launch(void* const* d_in, const int* in_sizes, int n_in,
                              void* d_out, int out_size, void* d_ws, size_t ws_size,
                              hipStream_t stream) {
  const int*   x_in  = (const int*)d_in[0];
  const int*   x_len = (const int*)d_in[1];
  const float* emb   = (const float*)d_in[2];
  const float* W_ih  = (const float*)d_in[3];
  const float* W_hh  = (const float*)d_in[4];
  const float* b_ih  = (const float*)d_in[5];
  const float* b_hh  = (const float*)d_in[6];
  const float* fc1_w = (const float*)d_in[7];
  const float* fc1_b = (const float*)d_in[8];
  const float* fc2_w = (const float*)d_in[9];
  const float* fc2_b = (const float*)d_in[10];
  float* out = (float*)d_out;

  float* T = (float*)d_ws;  // 128*256 f32 = 128 KB

  prep_T<<<Vv, Hh, 0, stream>>>(emb, W_ih, b_ih, b_hh, T);
  rnn_fused<<<Bb / 16, 256, 0, stream>>>(x_in, x_len, W_hh, T,
                                         fc1_w, fc1_b, fc2_w, fc2_b, out);
}